// Round 1
// baseline (663.426 us; speedup 1.0000x reference)
//
#include <hip/hip_runtime.h>
#include <hip/hip_bf16.h>
#include <math.h>

// ---------------------------------------------------------------------------
// RotSSM: out[b,Do,t] = C2 @ scan(M @ u)[.,b,t] + D ⊙ u[b,.,t]
//   M  = P_h @ (norm_h * B_param_h)   (256x256, head-stacked)
//   scan: z_t = a*z_{t-1} + w_t per (head,pair), a = gamma_h * e^{i theta_hp}
//   C2 = C @ blockdiag(P_h^T)
// Chunked scan (L=64): carries are closed-form via (a^L)^k table -> no
// sequential cross-block dependency; 2 GEMM kernels + tiny precompute.
// ---------------------------------------------------------------------------

#define TLEN 4096
#define LCH 64
#define NCH 64            // TLEN / LCH
#define BSZ 8

// workspace float offsets
constexpr int MF_OFF   = 0;                              // Mfull   [256][256] f32
constexpr int C2_OFF   = 65536;                          // C2      [256][256] f32
constexpr int AP_OFF   = 131072;                         // Apow    [65][128] float2
constexpr int ALP_OFF  = AP_OFF  + (LCH + 1) * 256;      // ALpow   [65][128] float2
constexpr int TOT_OFF  = ALP_OFF + (NCH + 1) * 256;      // Tot     [64][8][128] float2
constexpr int PL_OFF   = TOT_OFF + NCH * 8 * 256;        // P       [64][4][4] f32
constexpr int NORM_OFF = PL_OFF  + 1024;                 // norm    [64] f32
constexpr int S_OFF    = NORM_OFF + 64;                  // states  [T][8][128] uint (2xbf16)
// total floats = S_OFF + 4096*8*128  (~17.2 MiB)

__device__ __forceinline__ float bfbits2f(unsigned int bits16) {
  union { unsigned int u; float f; } v; v.u = bits16 << 16; return v.f;
}
__device__ __forceinline__ unsigned int f2bfbits(float f) {
  union { float f; unsigned int u; } v; v.f = f;
  return (v.u + 0x7fffu + ((v.u >> 16) & 1u)) >> 16;   // RNE, finite inputs
}

// ---------------------------------------------------------------------------
// K0a: gamma, norm, expm(P_param - P_param^T), power tables. 1 block.
// ---------------------------------------------------------------------------
__global__ __launch_bounds__(256) void k0a_precompute(
    const float* __restrict__ thetas_log, const float* __restrict__ P_param,
    const float* __restrict__ B_param, const float* __restrict__ gamma_log,
    float* __restrict__ ws) {
  __shared__ float tracep[64][4];
  __shared__ double gamma_d[64];
  const int tid = threadIdx.x;
  {
    int h = tid >> 2, q = tid & 3;
    const float* bp = B_param + (h * 4 + q) * 256;
    float s = 0.f;
    for (int i = 0; i < 256; ++i) { float v = bp[i]; s += v * v; }
    tracep[h][q] = s;
  }
  __syncthreads();
  if (tid < 64) {
    int h = tid;
    double g = exp(-exp((double)gamma_log[h]));
    gamma_d[h] = g;
    double tr = (double)tracep[h][0] + tracep[h][1] + tracep[h][2] + tracep[h][3];
    ws[NORM_OFF + h] = (float)sqrt((1.0 - g * g) / tr);
    // expm of 4x4 skew: scale-square + Taylor (fp64)
    double A[4][4], E[4][4], Tm[4][4];
    for (int i = 0; i < 4; ++i)
      for (int j = 0; j < 4; ++j)
        A[i][j] = (double)P_param[h * 16 + i * 4 + j] - (double)P_param[h * 16 + j * 4 + i];
    double fro = 0.0;
    for (int i = 0; i < 4; ++i) for (int j = 0; j < 4; ++j) fro += A[i][j] * A[i][j];
    fro = sqrt(fro);
    int s = 0;
    while (fro > 0.25 && s < 30) { fro *= 0.5; ++s; }
    double scl = 1.0;
    for (int q2 = 0; q2 < s; ++q2) scl *= 0.5;
    for (int i = 0; i < 4; ++i) for (int j = 0; j < 4; ++j) A[i][j] *= scl;
    for (int i = 0; i < 4; ++i)
      for (int j = 0; j < 4; ++j) { E[i][j] = (i == j) ? 1.0 : 0.0; Tm[i][j] = E[i][j]; }
    for (int k = 1; k <= 16; ++k) {
      double Tn[4][4];
      for (int i = 0; i < 4; ++i)
        for (int j = 0; j < 4; ++j) {
          double acc = 0.0;
          for (int m = 0; m < 4; ++m) acc += Tm[i][m] * A[m][j];
          Tn[i][j] = acc / (double)k;
        }
      for (int i = 0; i < 4; ++i)
        for (int j = 0; j < 4; ++j) { Tm[i][j] = Tn[i][j]; E[i][j] += Tn[i][j]; }
    }
    for (int q2 = 0; q2 < s; ++q2) {
      double E2[4][4];
      for (int i = 0; i < 4; ++i)
        for (int j = 0; j < 4; ++j) {
          double acc = 0.0;
          for (int m = 0; m < 4; ++m) acc += E[i][m] * E[m][j];
          E2[i][j] = acc;
        }
      for (int i = 0; i < 4; ++i) for (int j = 0; j < 4; ++j) E[i][j] = E2[i][j];
    }
    for (int i = 0; i < 4; ++i)
      for (int j = 0; j < 4; ++j) ws[PL_OFF + h * 16 + i * 4 + j] = (float)E[i][j];
  }
  __syncthreads();
  if (tid < 128) {
    int h = tid >> 1, p = tid & 1;
    double th = exp((double)thetas_log[h * 2 + p]);
    double g = gamma_d[h];
    double ar = g * cos(th), ai = g * sin(th);
    float2* Apw = (float2*)(ws + AP_OFF);
    float2* ALp = (float2*)(ws + ALP_OFF);
    double xr = 1.0, xi = 0.0;
    Apw[tid] = make_float2(1.f, 0.f);
    for (int j = 1; j <= LCH; ++j) {
      double nr = xr * ar - xi * ai, ni = xr * ai + xi * ar;
      xr = nr; xi = ni;
      Apw[j * 128 + tid] = make_float2((float)xr, (float)xi);
    }
    double br = xr, bi = xi;   // a^L
    xr = 1.0; xi = 0.0;
    ALp[tid] = make_float2(1.f, 0.f);
    for (int k = 1; k <= NCH; ++k) {
      double nr = xr * br - xi * bi, ni = xr * bi + xi * br;
      xr = nr; xi = ni;
      ALp[k * 128 + tid] = make_float2((float)xr, (float)xi);
    }
  }
}

// ---------------------------------------------------------------------------
// K0b: Mfull = norm * (P @ B_param), C2 = C @ blockdiag(P^T). 32 blocks.
// ---------------------------------------------------------------------------
__global__ __launch_bounds__(256) void k0b_mats(
    const float* __restrict__ B_param, const float* __restrict__ C,
    float* __restrict__ ws) {
  const float* Pl  = ws + PL_OFF;
  const float* nrm = ws + NORM_OFF;
  const int blk = blockIdx.x, tid = threadIdx.x;
  if (blk < 16) {
    for (int rr = 0; rr < 16; ++rr) {
      int r = blk * 16 + rr, h = r >> 2, N = r & 3;
      float acc = 0.f;
      for (int n = 0; n < 4; ++n)
        acc += Pl[h * 16 + N * 4 + n] * B_param[(h * 4 + n) * 256 + tid];
      ws[MF_OFF + r * 256 + tid] = nrm[h] * acc;
    }
  } else {
    int h = tid >> 2, N = tid & 3;
    for (int rr = 0; rr < 16; ++rr) {
      int Do = (blk - 16) * 16 + rr;
      float acc = 0.f;
      for (int n = 0; n < 4; ++n)
        acc += C[Do * 256 + (tid & ~3) + n] * Pl[h * 16 + N * 4 + n];
      ws[C2_OFF + Do * 256 + tid] = acc;
    }
  }
}

// ---------------------------------------------------------------------------
// K1: per (chunk c, batch b): Ws = M @ u tile (fp32), local scan in LDS,
//     write local states (bf16 packed) + chunk totals (fp32).
// ---------------------------------------------------------------------------
__global__ __launch_bounds__(256) void k1_proj_scan(
    const float* __restrict__ u, float* __restrict__ ws) {
  __shared__ __align__(16) unsigned char smem[33024];     // union: ush | stu
  float (*ush)[64] = (float (*)[64])smem;                  // [128][64] fp32 (half K)
  unsigned int* stu = (unsigned int*)smem;                 // [64][129] packed 2xbf16
  const float*  Mf  = ws + MF_OFF;
  const float2* Apw = (const float2*)(ws + AP_OFF);
  float2*       Tot = (float2*)(ws + TOT_OFF);
  unsigned int* Sg  = (unsigned int*)(ws + S_OFF);
  const int c = blockIdx.x, b = blockIdx.y;
  const int t0 = c * LCH;
  const int tid = threadIdx.x;
  const int tt = tid & 63;
  const int rgu = __builtin_amdgcn_readfirstlane(tid >> 6); // wave-uniform row base
  const int r0 = rgu * 64;

  float acc[64];
#pragma unroll
  for (int j = 0; j < 64; ++j) acc[j] = 0.f;

  const int lrow = tid >> 4;
  const int lt4 = (tid & 15) * 4;
  for (int half = 0; half < 2; ++half) {
    const int dbase = half * 128;
#pragma unroll
    for (int i = 0; i < 8; ++i) {
      int row = lrow + i * 16;
      float4 v = *(const float4*)(u + (size_t)(b * 256 + dbase + row) * TLEN + t0 + lt4);
      *(float4*)&ush[row][lt4] = v;
    }
    __syncthreads();
    for (int d0 = 0; d0 < 128; d0 += 4) {
      float u0 = ush[d0 + 0][tt], u1 = ush[d0 + 1][tt];
      float u2 = ush[d0 + 2][tt], u3 = ush[d0 + 3][tt];
#pragma unroll
      for (int j = 0; j < 64; ++j) {
        const float4 m = *(const float4*)(Mf + (r0 + j) * 256 + dbase + d0);
        acc[j] = fmaf(m.x, u0, fmaf(m.y, u1, fmaf(m.z, u2, fmaf(m.w, u3, acc[j]))));
      }
    }
    __syncthreads();
  }
  // Ws -> LDS as packed bf16 pairs: stu[t][r/2]
#pragma unroll
  for (int j = 0; j < 64; j += 2) {
    unsigned int lo = f2bfbits(acc[j]);
    unsigned int hi = f2bfbits(acc[j + 1]);
    stu[tt * 129 + ((r0 + j) >> 1)] = lo | (hi << 16);
  }
  __syncthreads();
  // local scan: z_t = a*z + w_t (fp32 state, bf16 storage)
  if (tid < 128) {
    const int p = tid;
    float2 a = Apw[128 + p];       // a^1
    float zr = 0.f, zi = 0.f;
    for (int t = 0; t < LCH; ++t) {
      unsigned int w = stu[t * 129 + p];
      float wr = bfbits2f(w & 0xffffu);
      float wi = bfbits2f(w >> 16);
      float nr = fmaf(a.x, zr, fmaf(-a.y, zi, wr));
      float ni = fmaf(a.x, zi, fmaf(a.y, zr, wi));
      zr = nr; zi = ni;
      stu[t * 129 + p] = f2bfbits(zr) | (f2bfbits(zi) << 16);
    }
    Tot[(c * BSZ + b) * 128 + p] = make_float2(zr, zi);
  }
  __syncthreads();
  // local states -> global S[t][b][128] (uint = 2 bf16)
#pragma unroll
  for (int i = 0; i < 32; ++i) {
    int idx = tid + 256 * i;
    int t = idx >> 7, q = idx & 127;
    Sg[(size_t)(t0 + t) * 1024 + b * 128 + q] = stu[t * 129 + q];
  }
}

// ---------------------------------------------------------------------------
// K3: per (chunk c, batch b): carry (closed form), correction, GEMM2 + D⊙u.
// ---------------------------------------------------------------------------
__global__ __launch_bounds__(256) void k3_out(
    const float* __restrict__ u, const float* __restrict__ Dv,
    const float* __restrict__ ws, float* __restrict__ out) {
  __shared__ __align__(16) unsigned char smem[33024];
  unsigned int* stu = (unsigned int*)smem;                 // [64][129]
  const float*  C2  = ws + C2_OFF;
  const float2* Apw = (const float2*)(ws + AP_OFF);
  const float2* ALp = (const float2*)(ws + ALP_OFF);
  const float2* Tot = (const float2*)(ws + TOT_OFF);
  const unsigned int* Sg = (const unsigned int*)(ws + S_OFF);
  const int c = blockIdx.x, b = blockIdx.y;
  const int t0 = c * LCH;
  const int tid = threadIdx.x;
  const int tt = tid & 63;
  const int rgu = __builtin_amdgcn_readfirstlane(tid >> 6);
  const int r0 = rgu * 64;

  // carry_c = sum_{c'<c} (a^L)^{c-1-c'} * Tot_{c'}
  float cr = 0.f, ci = 0.f;
  if (c > 0 && tid < 128) {
    for (int cp = 0; cp < c; ++cp) {
      float2 al = ALp[(c - 1 - cp) * 128 + tid];
      float2 tv = Tot[(cp * BSZ + b) * 128 + tid];
      cr = fmaf(al.x, tv.x, fmaf(-al.y, tv.y, cr));
      ci = fmaf(al.x, tv.y, fmaf(al.y, tv.x, ci));
    }
  }
  // load local states tile
#pragma unroll
  for (int i = 0; i < 32; ++i) {
    int idx = tid + 256 * i;
    int t = idx >> 7, q = idx & 127;
    stu[t * 129 + q] = Sg[(size_t)(t0 + t) * 1024 + b * 128 + q];
  }
  __syncthreads();
  // z_t += a^{t+1} * carry
  if (c > 0 && tid < 128) {
    const int p = tid;
    for (int t = 0; t < LCH; ++t) {
      float2 ap = Apw[(t + 1) * 128 + p];
      float dr = fmaf(ap.x, cr, -ap.y * ci);
      float di = fmaf(ap.x, ci, ap.y * cr);
      unsigned int w = stu[t * 129 + p];
      float sr = bfbits2f(w & 0xffffu) + dr;
      float si = bfbits2f(w >> 16) + di;
      stu[t * 129 + p] = f2bfbits(sr) | (f2bfbits(si) << 16);
    }
  }
  __syncthreads();
  // out[b, Do, t] = C2 @ z + D*u
  float acc[64];
#pragma unroll
  for (int j = 0; j < 64; ++j) acc[j] = 0.f;
  for (int k0 = 0; k0 < 256; k0 += 4) {
    unsigned int u01 = stu[tt * 129 + (k0 >> 1)];
    unsigned int u23 = stu[tt * 129 + (k0 >> 1) + 1];
    float s0 = bfbits2f(u01 & 0xffffu), s1 = bfbits2f(u01 >> 16);
    float s2 = bfbits2f(u23 & 0xffffu), s3 = bfbits2f(u23 >> 16);
#pragma unroll
    for (int j = 0; j < 64; ++j) {
      const float4 m = *(const float4*)(C2 + (r0 + j) * 256 + k0);
      acc[j] = fmaf(m.x, s0, fmaf(m.y, s1, fmaf(m.z, s2, fmaf(m.w, s3, acc[j]))));
    }
  }
#pragma unroll
  for (int j = 0; j < 64; ++j) {
    int Do = r0 + j;
    size_t idx = (size_t)(b * 256 + Do) * TLEN + t0 + tt;
    out[idx] = acc[j] + Dv[Do] * u[idx];
  }
}

extern "C" void kernel_launch(void* const* d_in, const int* in_sizes, int n_in,
                              void* d_out, int out_size, void* d_ws, size_t ws_size,
                              hipStream_t stream) {
  const float* u          = (const float*)d_in[0];
  const float* thetas_log = (const float*)d_in[1];
  const float* P_param    = (const float*)d_in[2];
  const float* B_param    = (const float*)d_in[3];
  const float* C          = (const float*)d_in[4];
  const float* Dvec       = (const float*)d_in[5];
  const float* gamma_log  = (const float*)d_in[6];
  float* out = (float*)d_out;
  float* ws  = (float*)d_ws;

  hipLaunchKernelGGL(k0a_precompute, dim3(1), dim3(256), 0, stream,
                     thetas_log, P_param, B_param, gamma_log, ws);
  hipLaunchKernelGGL(k0b_mats, dim3(32), dim3(256), 0, stream, B_param, C, ws);
  hipLaunchKernelGGL(k1_proj_scan, dim3(NCH, BSZ), dim3(256), 0, stream, u, ws);
  hipLaunchKernelGGL(k3_out, dim3(NCH, BSZ), dim3(256), 0, stream, u, Dvec, ws, out);
}

// Round 4
// 169.864 us; speedup vs baseline: 3.9056x; 3.9056x over previous
//
#include <hip/hip_runtime.h>
#include <hip/hip_bf16.h>
#include <math.h>

// ---------------------------------------------------------------------------
// RotSSM: out[b,Do,t] = C2 @ scan(M @ u)[.,b,t] + D ⊙ u[b,.,t]
// MFMA split version, swizzle-free staging:
//   - M, C2 kept row-major bf16 in ws; A-frags = direct short8 loads.
//   - u / z staged as row-major [t][k] bf16 LDS tiles; B-frags = short8 row
//     reads (n = lane&15). u tile uses an 8-wide XOR column swizzle to cut
//     staging bank conflicts; z tile needs none.
//   Frag formulas (guide, HW-verified): A[m=L&15][k=(L>>4)*8+j],
//   B[k=(L>>4)*8+j][n=L&15], D col=L&15, row=(L>>4)*4+reg.
// ---------------------------------------------------------------------------

typedef __attribute__((ext_vector_type(8))) short short8;   // 8 bf16 (4 VGPRs)
typedef __attribute__((ext_vector_type(4))) float f32x4;

#define TLEN 4096
#define LCH 64
#define NCH 64
#define BSZ 8
#define LDK 264          // shorts per [t] row (256 + 8 pad, keeps 16B align)
#define LDW 132          // dwords per [t] row (= LDK/2)

// workspace float offsets
constexpr int MB_OFF   = 0;                           // M bf16 row-major [256][256] (65536 sh)
constexpr int CB_OFF   = 32768;                       // C2 bf16 row-major
constexpr int AP_OFF   = 65536;                       // Apow  [65][128] float2
constexpr int ALP_OFF  = AP_OFF + 65 * 256;           // ALpow [65][128] float2
constexpr int TOT_OFF  = ALP_OFF + 65 * 256;          // Tot [64][8][128] float2
constexpr int PL_OFF   = TOT_OFF + NCH * BSZ * 256;   // P [64][4][4]
constexpr int NORM_OFF = PL_OFF + 1024;               // norm [64]
constexpr int S_OFF    = NORM_OFF + 64;               // states [T][8][128] uint(2xbf16)

__device__ __forceinline__ float bfbits2f(unsigned int bits16) {
  union { unsigned int u; float f; } v; v.u = bits16 << 16; return v.f;
}
__device__ __forceinline__ unsigned int f2bfbits(float f) {
  union { float f; unsigned int u; } v; v.f = f;
  return (v.u + 0x7fffu + ((v.u >> 16) & 1u)) >> 16;   // RNE, finite inputs
}
__device__ __forceinline__ unsigned int pack2(float x, float y) {
  return f2bfbits(x) | (f2bfbits(y) << 16);
}

// ---------------------------------------------------------------------------
// K0a: gamma, norm, expm(skew), power tables. 1 block. (verified round 1)
// ---------------------------------------------------------------------------
__global__ __launch_bounds__(256) void k0a_precompute(
    const float* __restrict__ thetas_log, const float* __restrict__ P_param,
    const float* __restrict__ B_param, const float* __restrict__ gamma_log,
    float* __restrict__ ws) {
  __shared__ float tracep[64][4];
  __shared__ double gamma_d[64];
  const int tid = threadIdx.x;
  {
    int h = tid >> 2, q = tid & 3;
    const float* bp = B_param + (h * 4 + q) * 256;
    float s = 0.f;
    for (int i = 0; i < 256; ++i) { float v = bp[i]; s += v * v; }
    tracep[h][q] = s;
  }
  __syncthreads();
  if (tid < 64) {
    int h = tid;
    double g = exp(-exp((double)gamma_log[h]));
    gamma_d[h] = g;
    double tr = (double)tracep[h][0] + tracep[h][1] + tracep[h][2] + tracep[h][3];
    ws[NORM_OFF + h] = (float)sqrt((1.0 - g * g) / tr);
    double A[4][4], E[4][4], Tm[4][4];
    for (int i = 0; i < 4; ++i)
      for (int j = 0; j < 4; ++j)
        A[i][j] = (double)P_param[h * 16 + i * 4 + j] - (double)P_param[h * 16 + j * 4 + i];
    double fro = 0.0;
    for (int i = 0; i < 4; ++i) for (int j = 0; j < 4; ++j) fro += A[i][j] * A[i][j];
    fro = sqrt(fro);
    int s = 0;
    while (fro > 0.25 && s < 30) { fro *= 0.5; ++s; }
    double scl = 1.0;
    for (int q2 = 0; q2 < s; ++q2) scl *= 0.5;
    for (int i = 0; i < 4; ++i) for (int j = 0; j < 4; ++j) A[i][j] *= scl;
    for (int i = 0; i < 4; ++i)
      for (int j = 0; j < 4; ++j) { E[i][j] = (i == j) ? 1.0 : 0.0; Tm[i][j] = E[i][j]; }
    for (int k = 1; k <= 16; ++k) {
      double Tn[4][4];
      for (int i = 0; i < 4; ++i)
        for (int j = 0; j < 4; ++j) {
          double acc = 0.0;
          for (int m = 0; m < 4; ++m) acc += Tm[i][m] * A[m][j];
          Tn[i][j] = acc / (double)k;
        }
      for (int i = 0; i < 4; ++i)
        for (int j = 0; j < 4; ++j) { Tm[i][j] = Tn[i][j]; E[i][j] += Tn[i][j]; }
    }
    for (int q2 = 0; q2 < s; ++q2) {
      double E2[4][4];
      for (int i = 0; i < 4; ++i)
        for (int j = 0; j < 4; ++j) {
          double acc = 0.0;
          for (int m = 0; m < 4; ++m) acc += E[i][m] * E[m][j];
          E2[i][j] = acc;
        }
      for (int i = 0; i < 4; ++i) for (int j = 0; j < 4; ++j) E[i][j] = E2[i][j];
    }
    for (int i = 0; i < 4; ++i)
      for (int j = 0; j < 4; ++j) ws[PL_OFF + h * 16 + i * 4 + j] = (float)E[i][j];
  }
  __syncthreads();
  if (tid < 128) {
    int h = tid >> 1, p = tid & 1;
    double th = exp((double)thetas_log[h * 2 + p]);
    double g = gamma_d[h];
    double ar = g * cos(th), ai = g * sin(th);
    float2* Apw = (float2*)(ws + AP_OFF);
    float2* ALp = (float2*)(ws + ALP_OFF);
    double xr = 1.0, xi = 0.0;
    Apw[tid] = make_float2(1.f, 0.f);
    for (int j = 1; j <= LCH; ++j) {
      double nr = xr * ar - xi * ai, ni = xr * ai + xi * ar;
      xr = nr; xi = ni;
      Apw[j * 128 + tid] = make_float2((float)xr, (float)xi);
    }
    double br = xr, bi = xi;   // a^L
    xr = 1.0; xi = 0.0;
    ALp[tid] = make_float2(1.f, 0.f);
    for (int k = 1; k <= NCH; ++k) {
      double nr = xr * br - xi * bi, ni = xr * bi + xi * br;
      xr = nr; xi = ni;
      ALp[k * 128 + tid] = make_float2((float)xr, (float)xi);
    }
  }
}

// ---------------------------------------------------------------------------
// K0b: M = norm*(P@B), C2 = C@blockdiag(P^T) -> plain row-major bf16.
// ---------------------------------------------------------------------------
__global__ __launch_bounds__(256) void k0b_mats(
    const float* __restrict__ B_param, const float* __restrict__ C,
    float* __restrict__ ws) {
  const float* Pl  = ws + PL_OFF;
  const float* nrm = ws + NORM_OFF;
  unsigned short* Mbf = (unsigned short*)(ws + MB_OFF);
  unsigned short* Cbf = (unsigned short*)(ws + CB_OFF);
  const int blk = blockIdx.x, tid = threadIdx.x;
  if (blk < 16) {
    for (int rr = 0; rr < 16; ++rr) {
      int r = blk * 16 + rr, h = r >> 2, N = r & 3;
      float acc = 0.f;
      for (int n = 0; n < 4; ++n)
        acc += Pl[h * 16 + N * 4 + n] * B_param[(h * 4 + n) * 256 + tid];
      Mbf[r * 256 + tid] = (unsigned short)f2bfbits(nrm[h] * acc);
    }
  } else {
    int h = tid >> 2;                 // tid = state-column index k = 4h+N
    int N = tid & 3;
    for (int rr = 0; rr < 16; ++rr) {
      int Do = (blk - 16) * 16 + rr;
      float acc = 0.f;
      for (int n = 0; n < 4; ++n)
        acc += C[Do * 256 + (tid & ~3) + n] * Pl[h * 16 + N * 4 + n];
      Cbf[Do * 256 + tid] = (unsigned short)f2bfbits(acc);
    }
  }
}

// ---------------------------------------------------------------------------
// K1: stage u [t][k] bf16 (XOR-8 col swizzle) -> MFMA GEMM1 -> W [t][k] bf16
//     -> local scan -> states + totals to global. LDS union 33792 B.
// ---------------------------------------------------------------------------
__global__ __launch_bounds__(256) void k1_mfma(
    const float* __restrict__ u, float* __restrict__ ws) {
  __shared__ __align__(16) unsigned char smem[64 * LDK * 2];   // 33792 B
  unsigned short* us = (unsigned short*)smem;   // u tile [t][LDK]
  unsigned int*   wd = (unsigned int*)smem;     // W/scan [t][LDW] dwords

  const int c = blockIdx.x, b = blockIdx.y;
  const int t0 = c * LCH;
  const int tid = threadIdx.x;
  const int L = tid & 63;
  const int w = __builtin_amdgcn_readfirstlane(tid >> 6);
  const int qh = L >> 4, l15 = L & 15;

  // ---- stage u[d][t0+t] -> us[t][d ^ ((t&3)<<3)] ----
  {
    const int kbase = tid >> 4;             // d low bits
    const int t4 = (tid & 15) * 4;
#pragma unroll
    for (int i = 0; i < 16; ++i) {
      int d = kbase + i * 16;
      float4 v = *(const float4*)(u + (size_t)(b * 256 + d) * TLEN + t0 + t4);
      float vv[4] = {v.x, v.y, v.z, v.w};
#pragma unroll
      for (int dt = 0; dt < 4; ++dt) {
        int t = t4 + dt;
        us[t * LDK + (d ^ ((t & 3) << 3))] = (unsigned short)f2bfbits(vv[dt]);
      }
    }
  }
  __syncthreads();

  // ---- GEMM1: W[256][64] = M @ u_tile ----
  f32x4 acc[4][4];
#pragma unroll
  for (int rt = 0; rt < 4; ++rt)
#pragma unroll
    for (int tt = 0; tt < 4; ++tt) acc[rt][tt] = (f32x4){0.f, 0.f, 0.f, 0.f};
  {
    const unsigned short* Mbf = (const unsigned short*)(ws + MB_OFF);
#pragma unroll
    for (int ks = 0; ks < 8; ++ks) {
      short8 af[4], bf[4];
#pragma unroll
      for (int rt = 0; rt < 4; ++rt)
        af[rt] = *(const short8*)(Mbf + (size_t)(w * 64 + rt * 16 + l15) * 256 + ks * 32 + qh * 8);
#pragma unroll
      for (int tt = 0; tt < 4; ++tt) {
        int row = tt * 16 + l15;
        int col = (ks * 32 + qh * 8) ^ ((row & 3) << 3);
        bf[tt] = *(const short8*)(us + row * LDK + col);
      }
#pragma unroll
      for (int rt = 0; rt < 4; ++rt)
#pragma unroll
        for (int tt = 0; tt < 4; ++tt)
          acc[rt][tt] = __builtin_amdgcn_mfma_f32_16x16x32_bf16(af[rt], bf[tt], acc[rt][tt], 0, 0, 0);
    }
  }
  __syncthreads();   // all us reads done before overwrite (alias)

  // ---- W -> wd[t][p] pair-packed bf16 (D: row=qh*4+q, col=l15) ----
#pragma unroll
  for (int rt = 0; rt < 4; ++rt) {
    int pbase = w * 32 + rt * 8 + qh * 2;   // dword index = row/2
#pragma unroll
    for (int tt = 0; tt < 4; ++tt) {
      int t = tt * 16 + l15;
      f32x4 a4 = acc[rt][tt];
      wd[t * LDW + pbase]     = pack2(a4[0], a4[1]);
      wd[t * LDW + pbase + 1] = pack2(a4[2], a4[3]);
    }
  }
  __syncthreads();

  // ---- local scan (fp32 state, bf16 storage), chunk totals ----
  if (tid < 128) {
    const int p = tid;
    const float2* Apw = (const float2*)(ws + AP_OFF);
    float2 a = Apw[128 + p];       // a^1
    float zr = 0.f, zi = 0.f;
#pragma unroll
    for (int t = 0; t < LCH; ++t) {
      unsigned int wv = wd[t * LDW + p];
      float wr = bfbits2f(wv & 0xffffu), wi = bfbits2f(wv >> 16);
      float nr = fmaf(a.x, zr, fmaf(-a.y, zi, wr));
      float ni = fmaf(a.x, zi, fmaf(a.y, zr, wi));
      zr = nr; zi = ni;
      wd[t * LDW + p] = pack2(zr, zi);
    }
    ((float2*)(ws + TOT_OFF))[(c * BSZ + b) * 128 + p] = make_float2(zr, zi);
  }
  __syncthreads();

  // ---- states -> global Sg[t][b][128] ----
  unsigned int* Sg = (unsigned int*)(ws + S_OFF);
#pragma unroll
  for (int i = 0; i < 32; ++i) {
    int idx = tid + 256 * i;
    int t = idx >> 7, q = idx & 127;
    Sg[(size_t)(t0 + t) * 1024 + b * 128 + q] = wd[t * LDW + q];
  }
}

// ---------------------------------------------------------------------------
// K3: carry + correction -> z [t][k] bf16 LDS -> MFMA GEMM2 -> out.
// ---------------------------------------------------------------------------
__global__ __launch_bounds__(256) void k3_mfma(
    const float* __restrict__ u, const float* __restrict__ Dv,
    const float* __restrict__ ws, float* __restrict__ out) {
  __shared__ __align__(16) unsigned char smem[64 * LDK * 2];
  unsigned int* zd = (unsigned int*)smem;       // z tile [t][LDW] dwords

  const int c = blockIdx.x, b = blockIdx.y;
  const int t0 = c * LCH;
  const int tid = threadIdx.x;
  const int L = tid & 63;
  const int w = __builtin_amdgcn_readfirstlane(tid >> 6);
  const int qh = L >> 4, l15 = L & 15;
  const unsigned int* Sg = (const unsigned int*)(ws + S_OFF);

  // ---- carry (closed form) + correction -> zd[t][p] ----
  if (tid < 128) {
    const int p = tid;
    float cr = 0.f, ci = 0.f;
    const float2* ALp = (const float2*)(ws + ALP_OFF);
    const float2* Tot = (const float2*)(ws + TOT_OFF);
    for (int cp = 0; cp < c; ++cp) {
      float2 al = ALp[(c - 1 - cp) * 128 + p];
      float2 tv = Tot[(cp * BSZ + b) * 128 + p];
      cr = fmaf(al.x, tv.x, fmaf(-al.y, tv.y, cr));
      ci = fmaf(al.x, tv.y, fmaf(al.y, tv.x, ci));
    }
    const float2* Apw = (const float2*)(ws + AP_OFF);
#pragma unroll
    for (int t = 0; t < LCH; ++t) {
      unsigned int wv = Sg[(size_t)(t0 + t) * 1024 + b * 128 + p];
      float2 ap = Apw[(t + 1) * 128 + p];
      float sr = fmaf(ap.x, cr, fmaf(-ap.y, ci, bfbits2f(wv & 0xffffu)));
      float si = fmaf(ap.x, ci, fmaf(ap.y, cr, bfbits2f(wv >> 16)));
      zd[t * LDW + p] = pack2(sr, si);
    }
  }
  __syncthreads();

  // ---- GEMM2: out_tile = C2 @ Z ----
  f32x4 acc[4][4];
#pragma unroll
  for (int rt = 0; rt < 4; ++rt)
#pragma unroll
    for (int tt = 0; tt < 4; ++tt) acc[rt][tt] = (f32x4){0.f, 0.f, 0.f, 0.f};
  {
    const unsigned short* Cbf = (const unsigned short*)(ws + CB_OFF);
    const unsigned short* zs  = (const unsigned short*)smem;
#pragma unroll
    for (int ks = 0; ks < 8; ++ks) {
      short8 af[4], bf[4];
#pragma unroll
      for (int rt = 0; rt < 4; ++rt)
        af[rt] = *(const short8*)(Cbf + (size_t)(w * 64 + rt * 16 + l15) * 256 + ks * 32 + qh * 8);
#pragma unroll
      for (int tt = 0; tt < 4; ++tt)
        bf[tt] = *(const short8*)(zs + (tt * 16 + l15) * LDK + ks * 32 + qh * 8);
#pragma unroll
      for (int rt = 0; rt < 4; ++rt)
#pragma unroll
        for (int tt = 0; tt < 4; ++tt)
          acc[rt][tt] = __builtin_amdgcn_mfma_f32_16x16x32_bf16(af[rt], bf[tt], acc[rt][tt], 0, 0, 0);
    }
  }

  // ---- epilogue: out = acc + D ⊙ u ----
  float dv[4][4];
#pragma unroll
  for (int rt = 0; rt < 4; ++rt)
#pragma unroll
    for (int q = 0; q < 4; ++q) dv[rt][q] = Dv[w * 64 + rt * 16 + qh * 4 + q];
#pragma unroll
  for (int rt = 0; rt < 4; ++rt) {
    int Dbase = w * 64 + rt * 16 + qh * 4;
#pragma unroll
    for (int tt = 0; tt < 4; ++tt) {
      int t = tt * 16 + l15;
      f32x4 a4 = acc[rt][tt];
      size_t obase = (size_t)(b * 256 + Dbase) * TLEN + t0 + t;
#pragma unroll
      for (int q = 0; q < 4; ++q)
        out[obase + (size_t)q * TLEN] = a4[q] + dv[rt][q] * u[obase + (size_t)q * TLEN];
    }
  }
}

extern "C" void kernel_launch(void* const* d_in, const int* in_sizes, int n_in,
                              void* d_out, int out_size, void* d_ws, size_t ws_size,
                              hipStream_t stream) {
  const float* u          = (const float*)d_in[0];
  const float* thetas_log = (const float*)d_in[1];
  const float* P_param    = (const float*)d_in[2];
  const float* B_param    = (const float*)d_in[3];
  const float* C          = (const float*)d_in[4];
  const float* Dvec       = (const float*)d_in[5];
  const float* gamma_log  = (const float*)d_in[6];
  float* out = (float*)d_out;
  float* ws  = (float*)d_ws;

  hipLaunchKernelGGL(k0a_precompute, dim3(1), dim3(256), 0, stream,
                     thetas_log, P_param, B_param, gamma_log, ws);
  hipLaunchKernelGGL(k0b_mats, dim3(32), dim3(256), 0, stream, B_param, C, ws);
  hipLaunchKernelGGL(k1_mfma, dim3(NCH, BSZ), dim3(256), 0, stream, u, ws);
  hipLaunchKernelGGL(k3_mfma, dim3(NCH, BSZ), dim3(256), 0, stream, u, Dvec, ws, out);
}